// Round 7
// baseline (12.324 us; speedup 1.0000x reference)
//
#include <hip/hip_runtime.h>
#include <math.h>

// SinenetLayer: h[s,b,d] = a[d] * sum_t x[s,b,t] * sin( 2*pi*i(d)*f*(k_T[t]-tau) + phi[d] )
//   i(d) = d/4 + 1  (32 harmonics), f = exp(nlf*LOG_F_STD + LOG_F_MEAN)
//
// Identity 1: sin(A+phi) = sinA*cos(phi) + cosA*sin(phi)
//   -> 64 per-(s,b) sums (32 harmonics x {sin,cos}); D=128 is an epilogue.
// Identity 2: angle linear in t (step D = 2*pi*i*f*T_WAV) -> phasor rotation.
// Identity 3 (group-of-8): sum_j x_j sin(th+jD) = P sin(th) + Q cos(th),
//   P = sum_j x_j c_j, Q = sum_j x_j s_j, twiddles (c_j,s_j) precomputed.
//
// R7 = best-measured R5 structure (LDS-staged x, scalar group-of-8 loop)
//   + single-barrier fused reduce/epilogue + hw sin/cos for phi.
//   expf restored (R6's exp2f constant shifted f by ~1e-7 -> ~9e-3 rad at
//   angle~1e5, which was the absmax 0.224->0.332 regression).
//
// One block per (s,b). Lane l of wave w: harmonic (l&31)+1, t-chunk
// w*2+(l>>5) of length 80 (10 macro-steps of 8). One barrier total.

#define S_DIM 25
#define B_DIM 64
#define T_DIM 640
#define D_DIM 128
#define NCHUNK 8
#define CLEN (T_DIM / NCHUNK)   // 80

__global__ __launch_bounds__(256) void sinenet_kernel(
    const float* __restrict__ x,    // (S*B, T)
    const float* __restrict__ nlf,  // (S*B)
    const float* __restrict__ tau,  // (S*B)
    const float* __restrict__ a,    // (D)
    const float* __restrict__ phi,  // (D)
    float* __restrict__ out)        // (S*B, D)
{
    __shared__ float lds_x[T_DIM];
    __shared__ float2 red[NCHUNK][32];   // (Ssum, Csum) partials per chunk

    const int bid   = blockIdx.x;              // flat (s*B + b)
    const int tid   = threadIdx.x;
    const int lane  = tid & 63;
    const int wid   = tid >> 6;
    const int h     = lane & 31;               // harmonic index 0..31
    const int chunk = wid * 2 + (lane >> 5);   // 0..7
    const int t0    = chunk * CLEN;

    // stage x row into LDS, vectorized: 160 float4 loads (coalesced)
    if (tid < T_DIM / 4)
        reinterpret_cast<float4*>(lds_x)[tid] =
            reinterpret_cast<const float4*>(x + (size_t)bid * T_DIM)[tid];

    const float tau_v = tau[bid];
    const float f     = expf(nlf[bid] * 0.373288f + 5.02654f);  // == reference f
    const float i_f   = (float)(h + 1);
    const float T_WAV = 1.0f / 16000.0f;

    // per-step rotation in revolutions: frac(i*f*T_WAV) (exact mod-1)
    const float dr0 = i_f * (f * T_WAV);
    const float dr  = dr0 - floorf(dr0);
    const float sD  = __builtin_amdgcn_sinf(dr);   // sin(2*pi*dr)
    const float cD  = __builtin_amdgcn_cosf(dr);

    // group twiddles (c_j, s_j) = rot(j*D), j=1..7, and macro-step rot(8D)
    const float c1 = cD,                        s1 = sD;
    const float c2 = fmaf(c1, cD, -(s1 * sD)),  s2 = fmaf(s1, cD, c1 * sD);
    const float c3 = fmaf(c2, cD, -(s2 * sD)),  s3 = fmaf(s2, cD, c2 * sD);
    const float c4 = fmaf(c3, cD, -(s3 * sD)),  s4 = fmaf(s3, cD, c3 * sD);
    const float c5 = fmaf(c4, cD, -(s4 * sD)),  s5 = fmaf(s4, cD, c4 * sD);
    const float c6 = fmaf(c5, cD, -(s5 * sD)),  s6 = fmaf(s5, cD, c5 * sD);
    const float c7 = fmaf(c6, cD, -(s6 * sD)),  s7 = fmaf(s6, cD, c6 * sD);
    const float c8 = fmaf(c7, cD, -(s7 * sD)),  s8 = fmaf(s7, cD, c7 * sD);

    // initial phasor at t0: i * frac(f*(k_T[t0]-tau)) (integer harmonic -> exact)
    const float tv0 = (float)t0 * T_WAV - tau_v;
    const float ft0 = f * tv0;
    const float u0  = ft0 - floorf(ft0);
    const float p0  = i_f * u0;
    const float w0  = p0 - floorf(p0);
    float s = __builtin_amdgcn_sinf(w0);
    float c = __builtin_amdgcn_cosf(w0);

    __syncthreads();

    // 10 macro-steps of 8 samples (exact R5 hot loop — best measured)
    float acc_s = 0.0f, acc_c = 0.0f;
    const float4* __restrict__ xp4 = reinterpret_cast<const float4*>(&lds_x[t0]);
    #pragma unroll
    for (int m = 0; m < CLEN / 8; ++m) {
        const float4 xa = xp4[2 * m];       // broadcast b128 within half-wave
        const float4 xb = xp4[2 * m + 1];

        float P = xa.x;
        P = fmaf(xa.y, c1, P); P = fmaf(xa.z, c2, P); P = fmaf(xa.w, c3, P);
        P = fmaf(xb.x, c4, P); P = fmaf(xb.y, c5, P); P = fmaf(xb.z, c6, P);
        P = fmaf(xb.w, c7, P);

        float Q = xa.y * s1;
        Q = fmaf(xa.z, s2, Q); Q = fmaf(xa.w, s3, Q); Q = fmaf(xb.x, s4, Q);
        Q = fmaf(xb.y, s5, Q); Q = fmaf(xb.z, s6, Q); Q = fmaf(xb.w, s7, Q);

        acc_s = fmaf(s, P, acc_s); acc_s = fmaf(c, Q, acc_s);
        acc_c = fmaf(c, P, acc_c); acc_c = fmaf(-s, Q, acc_c);

        const float sn = fmaf(s, c8, c * s8);
        const float cn = fmaf(c, c8, -(s * s8));
        s = sn; c = cn;
    }

    red[chunk][h] = make_float2(acc_s, acc_c);
    __syncthreads();

    // wave 0: reduce 8 chunks, apply phi via angle-addition, store 2 d's/lane
    if (tid < 64) {
        const int hh = tid >> 1;             // harmonic for d=2*tid, 2*tid+1
        float2 v = red[0][hh];
        #pragma unroll
        for (int cc = 1; cc < NCHUNK; ++cc) {   // broadcast-pair reads, no conflict
            v.x += red[cc][hh].x;
            v.y += red[cc][hh].y;
        }
        const float2 ph2 = reinterpret_cast<const float2*>(phi)[tid];
        const float2 a2  = reinterpret_cast<const float2*>(a)[tid];
        float pr0 = ph2.x * 0.15915494309189535f;  pr0 -= floorf(pr0);
        float pr1 = ph2.y * 0.15915494309189535f;  pr1 -= floorf(pr1);
        const float o0 = a2.x * fmaf(__builtin_amdgcn_cosf(pr0), v.x,
                                     __builtin_amdgcn_sinf(pr0) * v.y);
        const float o1 = a2.y * fmaf(__builtin_amdgcn_cosf(pr1), v.x,
                                     __builtin_amdgcn_sinf(pr1) * v.y);
        reinterpret_cast<float2*>(out + (size_t)bid * D_DIM)[tid] =
            make_float2(o0, o1);
    }
}

extern "C" void kernel_launch(void* const* d_in, const int* in_sizes, int n_in,
                              void* d_out, int out_size, void* d_ws, size_t ws_size,
                              hipStream_t stream) {
    const float* x   = (const float*)d_in[0];  // (S,B,1,T)
    const float* nlf = (const float*)d_in[1];  // (S,B,1,1)
    const float* tau = (const float*)d_in[2];  // (S,B,1,1)
    const float* a   = (const float*)d_in[3];  // (D)
    const float* phi = (const float*)d_in[4];  // (D)
    float* out = (float*)d_out;                // (S,B,D)

    const int n_sb = S_DIM * B_DIM;            // 1600 blocks, one per (s,b)
    sinenet_kernel<<<n_sb, 256, 0, stream>>>(x, nlf, tau, a, phi, out);
}

// Round 8
// 9.483 us; speedup vs baseline: 1.2997x; 1.2997x over previous
//
#include <hip/hip_runtime.h>
#include <math.h>

// SinenetLayer: h[s,b,d] = a[d] * sum_t x[s,b,t] * sin( 2*pi*i(d)*f*(k_T[t]-tau) + phi[d] )
//   i(d) = d/4 + 1  (32 harmonics), f = exp(nlf*LOG_F_STD + LOG_F_MEAN)
//
// Identity 1: sin(A+phi) = sinA*cos(phi) + cosA*sin(phi)
//   -> 64 per-(s,b) reductions (32 harmonics x {sin,cos}); D=128 is an epilogue.
// Identity 2: angle is linear in t (step D = 2*pi*i*f*T_WAV) -> phasor rotation.
// Identity 3 (group-of-8): s_{t+j} = s_t*c_j + c_t*s_j with (c_j,s_j)
//   precomputed, so  sum_j x_j*s_{t+j} = s_t*P + c_t*Q,  P = sum x_j*c_j,
//   Q = sum x_j*s_j.  Per 8 samples: 14 FMA (P,Q) + 4 FMA (acc) + 4 (rotate 8D)
//   = 2.75 VALU/(harmonic,t), and 2x ds_read_b128 instead of 8x b32.
//
// R8 = R5 verbatim (best measured: 9.47 us). R6/R7 established that further
// structural edits land inside the ~8 us launch-overhead floor + noise band;
// this source is the empirical optimum.
//
// One block per (s,b). Lane l of wave w: harmonic h=(l&31)+1, t-chunk
// w*2+(l>>5) of length 80 (= 10 macro-steps of 8). LDS reduce -> 128 outputs.

#define S_DIM 25
#define B_DIM 64
#define T_DIM 640
#define D_DIM 128
#define NCHUNK 8
#define CLEN (T_DIM / NCHUNK)   // 80 = 10 * 8

__global__ __launch_bounds__(256) void sinenet_kernel(
    const float* __restrict__ x,    // (S*B, T)
    const float* __restrict__ nlf,  // (S*B)
    const float* __restrict__ tau,  // (S*B)
    const float* __restrict__ a,    // (D)
    const float* __restrict__ phi,  // (D)
    float* __restrict__ out)        // (S*B, D)
{
    __shared__ float lds_x[T_DIM];
    __shared__ float red[2][NCHUNK][32];
    __shared__ float fin[64];

    const int bid   = blockIdx.x;              // flat (s*B + b)
    const int tid   = threadIdx.x;
    const int lane  = tid & 63;
    const int wid   = tid >> 6;
    const int h     = lane & 31;               // harmonic index 0..31
    const int chunk = wid * 2 + (lane >> 5);   // 0..7
    const int t0    = chunk * CLEN;

    // stage x row into LDS, vectorized: 160 float4 loads (coalesced, 16B-aligned)
    if (tid < T_DIM / 4)
        reinterpret_cast<float4*>(lds_x)[tid] =
            reinterpret_cast<const float4*>(x + (size_t)bid * T_DIM)[tid];

    const float tau_v = tau[bid];
    const float f     = expf(nlf[bid] * 0.373288f + 5.02654f);  // == reference f
    const float i_f   = (float)(h + 1);
    const float T_WAV = 1.0f / 16000.0f;

    // per-step rotation angle in revolutions: frac(i*f*T_WAV) (exact mod-1)
    const float dr0 = i_f * (f * T_WAV);
    const float dr  = dr0 - floorf(dr0);
    const float sD  = __builtin_amdgcn_sinf(dr);   // sin(2*pi*dr)
    const float cD  = __builtin_amdgcn_cosf(dr);

    // group twiddles (c_j, s_j) = rot(j*D), j=1..7, and the macro-step rot(8D)
    const float c1 = cD,                        s1 = sD;
    const float c2 = fmaf(c1, cD, -(s1 * sD)),  s2 = fmaf(s1, cD, c1 * sD);
    const float c3 = fmaf(c2, cD, -(s2 * sD)),  s3 = fmaf(s2, cD, c2 * sD);
    const float c4 = fmaf(c3, cD, -(s3 * sD)),  s4 = fmaf(s3, cD, c3 * sD);
    const float c5 = fmaf(c4, cD, -(s4 * sD)),  s5 = fmaf(s4, cD, c4 * sD);
    const float c6 = fmaf(c5, cD, -(s5 * sD)),  s6 = fmaf(s5, cD, c5 * sD);
    const float c7 = fmaf(c6, cD, -(s6 * sD)),  s7 = fmaf(s6, cD, c6 * sD);
    const float c8 = fmaf(c7, cD, -(s7 * sD)),  s8 = fmaf(s7, cD, c7 * sD);

    // initial phasor at t0: i * frac(f*(k_T[t0]-tau))  (integer harmonic -> exact)
    const float tv0 = (float)t0 * T_WAV - tau_v;
    const float ft0 = f * tv0;
    const float u0  = ft0 - floorf(ft0);
    const float p0  = i_f * u0;
    const float w0  = p0 - floorf(p0);
    float s = __builtin_amdgcn_sinf(w0);
    float c = __builtin_amdgcn_cosf(w0);

    __syncthreads();

    // 10 macro-steps of 8 samples
    float acc_s = 0.0f, acc_c = 0.0f;
    const float4* __restrict__ xp4 = reinterpret_cast<const float4*>(&lds_x[t0]);
    #pragma unroll
    for (int m = 0; m < CLEN / 8; ++m) {
        const float4 xa = xp4[2 * m];       // broadcast b128 within half-wave
        const float4 xb = xp4[2 * m + 1];

        float P = xa.x;
        P = fmaf(xa.y, c1, P); P = fmaf(xa.z, c2, P); P = fmaf(xa.w, c3, P);
        P = fmaf(xb.x, c4, P); P = fmaf(xb.y, c5, P); P = fmaf(xb.z, c6, P);
        P = fmaf(xb.w, c7, P);

        float Q = xa.y * s1;
        Q = fmaf(xa.z, s2, Q); Q = fmaf(xa.w, s3, Q); Q = fmaf(xb.x, s4, Q);
        Q = fmaf(xb.y, s5, Q); Q = fmaf(xb.z, s6, Q); Q = fmaf(xb.w, s7, Q);

        acc_s = fmaf(s, P, acc_s); acc_s = fmaf(c, Q, acc_s);
        acc_c = fmaf(c, P, acc_c); acc_c = fmaf(-s, Q, acc_c);

        const float sn = fmaf(s, c8, c * s8);
        const float cn = fmaf(c, c8, -(s * s8));
        s = sn; c = cn;
    }

    red[0][chunk][h] = acc_s;
    red[1][chunk][h] = acc_c;
    __syncthreads();

    if (tid < 64) {
        const int part = tid >> 5, hh = tid & 31;
        float v = 0.0f;
        #pragma unroll
        for (int cc = 0; cc < NCHUNK; ++cc)
            v += red[part][cc][hh];
        fin[tid] = v;                        // [0..31]=Ssum, [32..63]=Csum
    }
    __syncthreads();

    // epilogue: h[d] = a[d]*(cos(phi)*Ssum + sin(phi)*Csum), hw sin/cos
    if (tid < D_DIM) {
        const int   i0 = tid >> 2;
        const float Ss = fin[i0];
        const float Cs = fin[32 + i0];
        float pr = phi[tid] * 0.15915494309189535f;   // phi/(2*pi)
        pr = pr - floorf(pr);
        const float sp = __builtin_amdgcn_sinf(pr);
        const float cp = __builtin_amdgcn_cosf(pr);
        out[(size_t)bid * D_DIM + tid] = a[tid] * fmaf(cp, Ss, sp * Cs);
    }
}

extern "C" void kernel_launch(void* const* d_in, const int* in_sizes, int n_in,
                              void* d_out, int out_size, void* d_ws, size_t ws_size,
                              hipStream_t stream) {
    const float* x   = (const float*)d_in[0];  // (S,B,1,T)
    const float* nlf = (const float*)d_in[1];  // (S,B,1,1)
    const float* tau = (const float*)d_in[2];  // (S,B,1,1)
    const float* a   = (const float*)d_in[3];  // (D)
    const float* phi = (const float*)d_in[4];  // (D)
    float* out = (float*)d_out;                // (S,B,D)

    const int n_sb = S_DIM * B_DIM;            // 1600 blocks, one per (s,b)
    sinenet_kernel<<<n_sb, 256, 0, stream>>>(x, nlf, tau, a, phi, out);
}